// Round 1
// 374.213 us; speedup vs baseline: 1.0318x; 1.0318x over previous
//
#include <hip/hip_runtime.h>

// SpecEMA: y[b,c,t,f] = x[b,c,t,f] / sqrt(s[b,t,f]),
//   s_t = ALPHA*s_{t-1} + (1-ALPHA)*(x[b,0,t,f]^2 + x[b,1,t,f]^2), s_{-1}=state[f]
// Outputs: y [64,2,4000,96] then final_state [64,1,96], flat-concatenated in d_out.
//
// Linear-scan chunk decomposition: s_out(chunk) = a^L * s_in + B_chunk.
// Phase 1 computes B_chunk per (chain, chunk); phase 3 recombines prefixes
// (cheap, L2/L3-resident B array) and does the normalizing scan.
//
// K=100/L=40 (was 50/80): doubles grid to ~600 blocks (2.3 blocks/CU,
// ~9 waves/CU) — the kernels were latency-bound at 1.15 blocks/CU, not
// BW-bound (poison fill hits 6.7 TB/s on this chip; we were at ~2.3).
// Phase 3 iterates chunks in REVERSE k order: phase1 reads x ascending in
// k, so reversing aligns phase3's consumption with L3 LRU recency.

namespace {
constexpr int Bdim = 64, Cdim = 2, Tdim = 4000, Fdim = 96;
constexpr int K = 100, L = 40;             // T = K * L
constexpr int FG = Fdim / 4;               // 24 float4 groups per (b, c, t)
constexpr int CHAINS = Bdim * FG;          // 1536 float4-chains
constexpr float kAlpha = 0.99f;
constexpr float kOneMinusAlpha = 0.01f;    // float(1.0 - 0.99)
constexpr float kAlphaL = 0.66897172f;     // 0.99^40

typedef float v4f __attribute__((ext_vector_type(4)));

__device__ __forceinline__ v4f ld4(const float* p) {
  return *reinterpret_cast<const v4f*>(p);
}
}  // namespace

// Phase 1: chunk-local EMA accumulation with s_in = 0.  One thread per
// (chain, chunk k) for k in [0, K-1); chunk K-1's B is never needed.
__global__ __launch_bounds__(256) void spec_ema_phase1(
    const float* __restrict__ x, float* __restrict__ bws) {
  const int g = blockIdx.x * 256 + threadIdx.x;   // [0, CHAINS*(K-1)), exact
  const int chain = g % CHAINS;
  const int k = g / CHAINS;
  const int b = chain / FG, fg = chain % FG;

  const size_t base =
      ((size_t)b * Cdim * Tdim + (size_t)k * L) * Fdim + (size_t)fg * 4;
  const float* p0 = x + base;                       // c = 0
  const float* p1 = p0 + (size_t)Tdim * Fdim;       // c = 1

  v4f s = 0.0f;
#pragma unroll 8
  for (int j = 0; j < L; ++j) {
    v4f x0 = ld4(p0 + (size_t)j * Fdim);
    v4f x1 = ld4(p1 + (size_t)j * Fdim);
    v4f abs2 = x0 * x0 + x1 * x1;
    s = s * kAlpha + abs2 * kOneMinusAlpha;
  }
  // layout: bws[k][chain] as float4  (g == k*CHAINS + chain)
  *reinterpret_cast<v4f*>(bws + (size_t)g * 4) = s;
}

// Phase 3: recombine chunk prefix, then scan + normalize + write.
// k runs in REVERSE block order so the x regions phase1 touched most
// recently (k near K-1) are consumed first while still L3-hot.
__global__ __launch_bounds__(256) void spec_ema_phase3(
    const float* __restrict__ x, const float* __restrict__ state,
    const float* __restrict__ bws, float* __restrict__ out) {
  const int g = blockIdx.x * 256 + threadIdx.x;   // [0, CHAINS*K), exact
  const int chain = g % CHAINS;
  const int k = (K - 1) - (g / CHAINS);
  const int b = chain / FG, fg = chain % FG;

  // s_in = a^(k*L) * s0 + sum_{m<k} a^((k-1-m)*L) * B_m
  v4f s = ld4(state + (size_t)fg * 4);
#pragma unroll 4
  for (int m = 0; m < k; ++m) {
    v4f bm = ld4(bws + ((size_t)m * CHAINS + chain) * 4);
    s = s * kAlphaL + bm;
  }

  const size_t base =
      ((size_t)b * Cdim * Tdim + (size_t)k * L) * Fdim + (size_t)fg * 4;
  const float* p0 = x + base;
  const float* p1 = p0 + (size_t)Tdim * Fdim;
  float* q0 = out + base;
  float* q1 = q0 + (size_t)Tdim * Fdim;

#pragma unroll 4
  for (int j = 0; j < L; ++j) {
    v4f x0 = ld4(p0 + (size_t)j * Fdim);
    v4f x1 = ld4(p1 + (size_t)j * Fdim);
    v4f abs2 = x0 * x0 + x1 * x1;
    s = s * kAlpha + abs2 * kOneMinusAlpha;
    v4f r;
    r.x = rsqrtf(s.x);
    r.y = rsqrtf(s.y);
    r.z = rsqrtf(s.z);
    r.w = rsqrtf(s.w);
    v4f y0 = x0 * r;
    v4f y1 = x1 * r;
    __builtin_nontemporal_store(y0, reinterpret_cast<v4f*>(q0 + (size_t)j * Fdim));
    __builtin_nontemporal_store(y1, reinterpret_cast<v4f*>(q1 + (size_t)j * Fdim));
  }

  if (k == K - 1) {
    // final_state [64, 1, 96] appended after y
    *reinterpret_cast<v4f*>(out + (size_t)Bdim * Cdim * Tdim * Fdim +
                            (size_t)b * Fdim + (size_t)fg * 4) = s;
  }
}

extern "C" void kernel_launch(void* const* d_in, const int* in_sizes, int n_in,
                              void* d_out, int out_size, void* d_ws, size_t ws_size,
                              hipStream_t stream) {
  const float* x = (const float*)d_in[0];      // [64, 2, 4000, 96] f32
  const float* state = (const float*)d_in[1];  // [1, 1, 96] f32
  float* out = (float*)d_out;
  float* bws = (float*)d_ws;                   // needs CHAINS*(K-1)*16 B ~= 2.43 MB

  spec_ema_phase1<<<CHAINS * (K - 1) / 256, 256, 0, stream>>>(x, bws);
  spec_ema_phase3<<<CHAINS * K / 256, 256, 0, stream>>>(x, state, bws, out);
}